// Round 1
// baseline (1215.829 us; speedup 1.0000x reference)
//
#include <hip/hip_runtime.h>

// RNN: h_{t+1} = tanh(x_t * w_in + h_t @ W_hh^T + (b_ih + b_hh)); out = h_T @ fc_W^T + fc_b
// B = out_size (8192), T = in_sizes[0]/B (4096), H = 10 (compile-time).
//
// Design (round 0 baseline): one thread per batch element. Only 8192 threads
// exist (128 waves) -> parallelism-bound, not BW-bound. 64-thread blocks to
// spread 128 blocks across 128 CUs. Weights pre-scaled by 2*log2(e) so
// tanh(a) = 1 - 2*rcp(exp2(a') + 1) costs 1 exp + 1 rcp + 2 VALU per unit.

#define H 10

#if __has_builtin(__builtin_amdgcn_exp2f)
__device__ __forceinline__ float fast_exp2(float x) { return __builtin_amdgcn_exp2f(x); }
#else
__device__ __forceinline__ float fast_exp2(float x) { return __exp2f(x); }
#endif

#if __has_builtin(__builtin_amdgcn_rcpf)
__device__ __forceinline__ float fast_rcp(float x) { return __builtin_amdgcn_rcpf(x); }
#else
__device__ __forceinline__ float fast_rcp(float x) { return 1.0f / x; }
#endif

__global__ __launch_bounds__(64, 1) void rnn_fused(
    const float* __restrict__ x,
    const float* __restrict__ W_ih,
    const float* __restrict__ W_hh,
    const float* __restrict__ b_ih,
    const float* __restrict__ b_hh,
    const float* __restrict__ fc_W,
    const float* __restrict__ fc_b,
    float* __restrict__ out,
    int B, int T)
{
    const int b = blockIdx.x * 64 + threadIdx.x;
    if (b >= B) return;

    // 2*log2(e): pre-scale weights so the tanh argument is already the exp2 input.
    const float C = 2.8853900817779268f;

    float Wp[H][H], winp[H], biasp[H];
#pragma unroll
    for (int j = 0; j < H; ++j) {
        winp[j]  = C * W_ih[j];              // W_ih is (H,1) -> column 0
        biasp[j] = C * (b_ih[j] + b_hh[j]);
#pragma unroll
        for (int k = 0; k < H; ++k) Wp[j][k] = C * W_hh[j * H + k];
    }

    float h[H];
#pragma unroll
    for (int j = 0; j < H; ++j) h[j] = 0.0f;

    const float* xr = x + (size_t)b * (size_t)T;

    const int T4 = T & ~3;
    float4 xv = make_float4(0.f, 0.f, 0.f, 0.f);
    if (T4 > 0) xv = *(const float4*)(xr);

    for (int t = 0; t < T4; t += 4) {
        // software prefetch of the next 4 timesteps (one-iteration distance)
        float4 xn = xv;
        if (t + 4 < T4) xn = *(const float4*)(xr + t + 4);

        float xs[4] = {xv.x, xv.y, xv.z, xv.w};
#pragma unroll
        for (int q = 0; q < 4; ++q) {
            float nh[H];
#pragma unroll
            for (int j = 0; j < H; ++j) {
                float a = __builtin_fmaf(xs[q], winp[j], biasp[j]);
#pragma unroll
                for (int k = 0; k < H; ++k)
                    a = __builtin_fmaf(h[k], Wp[j][k], a);
                // tanh(a/C') = 1 - 2/(exp2(a)+1); saturates correctly at +-1
                float e = fast_exp2(a);
                float r = fast_rcp(e + 1.0f);
                nh[j] = __builtin_fmaf(-2.0f, r, 1.0f);
            }
#pragma unroll
            for (int j = 0; j < H; ++j) h[j] = nh[j];
        }
        xv = xn;
    }

    // remainder steps (T % 4), not taken for T=4096 but kept for robustness
    for (int t = T4; t < T; ++t) {
        float xq = xr[t];
        float nh[H];
#pragma unroll
        for (int j = 0; j < H; ++j) {
            float a = __builtin_fmaf(xq, winp[j], biasp[j]);
#pragma unroll
            for (int k = 0; k < H; ++k)
                a = __builtin_fmaf(h[k], Wp[j][k], a);
            float e = fast_exp2(a);
            float r = fast_rcp(e + 1.0f);
            nh[j] = __builtin_fmaf(-2.0f, r, 1.0f);
        }
#pragma unroll
        for (int j = 0; j < H; ++j) h[j] = nh[j];
    }

    float acc = fc_b[0];
#pragma unroll
    for (int j = 0; j < H; ++j) acc = __builtin_fmaf(h[j], fc_W[j], acc);
    out[b] = acc;
}

extern "C" void kernel_launch(void* const* d_in, const int* in_sizes, int n_in,
                              void* d_out, int out_size, void* d_ws, size_t ws_size,
                              hipStream_t stream) {
    const float* x    = (const float*)d_in[0];
    const float* W_ih = (const float*)d_in[1];
    const float* W_hh = (const float*)d_in[2];
    const float* b_ih = (const float*)d_in[3];
    const float* b_hh = (const float*)d_in[4];
    const float* fc_W = (const float*)d_in[5];
    const float* fc_b = (const float*)d_in[6];
    float* out = (float*)d_out;

    const int B = out_size;              // 8192
    const int T = in_sizes[0] / B;       // 4096

    const int threads = 64;
    const int blocks = (B + threads - 1) / threads;
    rnn_fused<<<blocks, threads, 0, stream>>>(x, W_ih, W_hh, b_ih, b_hh,
                                              fc_W, fc_b, out, B, T);
}

// Round 2
// 468.395 us; speedup vs baseline: 2.5957x; 2.5957x over previous
//
#include <hip/hip_runtime.h>

// RNN: h_{t+1} = tanh(x_t * w_in + h_t @ W_hh^T + (b_ih+b_hh)); out = h_T @ fc_W^T + fc_b
// B = out_size (8192), T = in_sizes[0]/B (4096), H = 10.
//
// R2 design: 4 lanes (one quad) per batch element; each lane owns 3 of 12
// hidden units (units 10,11 are zero-weight dummies). Per step the 10 live h
// values are exchanged via DPP quad_perm broadcasts (full-rate VALU).
// 32768 threads = 512 waves -> 512 of 1024 SIMDs busy (vs 128 in R1).
// tanh(a) = 1 - 2*rcp(exp2(a')+1), weights pre-scaled by 2*log2(e).

#define H 10
#define UPL 3  // units per lane (4 lanes * 3 = 12 >= H)

#if __has_builtin(__builtin_amdgcn_exp2f)
__device__ __forceinline__ float fast_exp2(float x) { return __builtin_amdgcn_exp2f(x); }
#else
__device__ __forceinline__ float fast_exp2(float x) { return __exp2f(x); }
#endif

#if __has_builtin(__builtin_amdgcn_rcpf)
__device__ __forceinline__ float fast_rcp(float x) { return __builtin_amdgcn_rcpf(x); }
#else
__device__ __forceinline__ float fast_rcp(float x) { return 1.0f / x; }
#endif

#if __has_builtin(__builtin_amdgcn_mov_dpp)
#define HAVE_DPP 1
// quad_perm:[P,P,P,P] -> broadcast lane P of each quad; ctrl = P * 0x55
template <int CTRL>
__device__ __forceinline__ float dpp_qperm(float v) {
    int r = __builtin_amdgcn_mov_dpp(__builtin_bit_cast(int, v), CTRL, 0xF, 0xF, true);
    return __builtin_bit_cast(float, r);
}
template <int P>
__device__ __forceinline__ float quad_bcast(float v) { return dpp_qperm<P * 0x55>(v); }
__device__ __forceinline__ float quad_swap1(float v) { return dpp_qperm<0xB1>(v); } // [1,0,3,2]
__device__ __forceinline__ float quad_swap2(float v) { return dpp_qperm<0x4E>(v); } // [2,3,0,1]
#else
template <int P>
__device__ __forceinline__ float quad_bcast(float v) {
    return __shfl(v, (threadIdx.x & ~3) | P, 64);
}
__device__ __forceinline__ float quad_swap1(float v) { return __shfl_xor(v, 1, 64); }
__device__ __forceinline__ float quad_swap2(float v) { return __shfl_xor(v, 2, 64); }
#endif

__global__ __launch_bounds__(64) void rnn_quad(
    const float* __restrict__ x,
    const float* __restrict__ W_ih,
    const float* __restrict__ W_hh,
    const float* __restrict__ b_ih,
    const float* __restrict__ b_hh,
    const float* __restrict__ fc_W,
    const float* __restrict__ fc_b,
    float* __restrict__ out,
    int B, int T)
{
    const int tid = blockIdx.x * 64 + threadIdx.x;
    const int b   = tid >> 2;        // batch element
    const int q   = tid & 3;         // lane-in-quad
    if (b >= B) return;

    const float C = 2.8853900817779268f;  // 2*log2(e)

    // Per-lane weight slices for units u = 3q + i (zero for dummy u >= H).
    float Wp[UPL][H], winp[UPL], biasp[UPL];
#pragma unroll
    for (int i = 0; i < UPL; ++i) {
        const int u = 3 * q + i;
        const bool live = (u < H);
        winp[i]  = live ? C * W_ih[u] : 0.0f;
        biasp[i] = live ? C * (b_ih[u] + b_hh[u]) : 0.0f;
#pragma unroll
        for (int k = 0; k < H; ++k)
            Wp[i][k] = live ? C * W_hh[u * H + k] : 0.0f;
    }

    float hl[UPL];  // this lane's hidden units
#pragma unroll
    for (int i = 0; i < UPL; ++i) hl[i] = 0.0f;

    const float* xr = x + (size_t)b * (size_t)T;
    const int T4 = T & ~3;
    float4 xv = make_float4(0.f, 0.f, 0.f, 0.f);
    if (T4 > 0) xv = *(const float4*)(xr);   // all 4 lanes: same address (L1 broadcast)

    for (int t = 0; t < T4; t += 4) {
        float4 xn = xv;
        if (t + 4 < T4) xn = *(const float4*)(xr + t + 4);
        float xs[4] = {xv.x, xv.y, xv.z, xv.w};

#pragma unroll
        for (int s = 0; s < 4; ++s) {
            // Broadcast the 10 live h values across the quad (DPP, full-rate).
            float hb[H];
            hb[0] = quad_bcast<0>(hl[0]); hb[1] = quad_bcast<0>(hl[1]); hb[2] = quad_bcast<0>(hl[2]);
            hb[3] = quad_bcast<1>(hl[0]); hb[4] = quad_bcast<1>(hl[1]); hb[5] = quad_bcast<1>(hl[2]);
            hb[6] = quad_bcast<2>(hl[0]); hb[7] = quad_bcast<2>(hl[1]); hb[8] = quad_bcast<2>(hl[2]);
            hb[9] = quad_bcast<3>(hl[0]);

#pragma unroll
            for (int i = 0; i < UPL; ++i) {
                float a = __builtin_fmaf(xs[s], winp[i], biasp[i]);
#pragma unroll
                for (int k = 0; k < H; ++k)
                    a = __builtin_fmaf(hb[k], Wp[i][k], a);
                float e = fast_exp2(a);
                float r = fast_rcp(e + 1.0f);
                hl[i] = __builtin_fmaf(-2.0f, r, 1.0f);   // tanh, saturation-safe
            }
        }
        xv = xn;
    }

    for (int t = T4; t < T; ++t) {  // remainder (not taken for T=4096)
        float xq = xr[t];
        float hb[H];
        hb[0] = quad_bcast<0>(hl[0]); hb[1] = quad_bcast<0>(hl[1]); hb[2] = quad_bcast<0>(hl[2]);
        hb[3] = quad_bcast<1>(hl[0]); hb[4] = quad_bcast<1>(hl[1]); hb[5] = quad_bcast<1>(hl[2]);
        hb[6] = quad_bcast<2>(hl[0]); hb[7] = quad_bcast<2>(hl[1]); hb[8] = quad_bcast<2>(hl[2]);
        hb[9] = quad_bcast<3>(hl[0]);
#pragma unroll
        for (int i = 0; i < UPL; ++i) {
            float a = __builtin_fmaf(xq, winp[i], biasp[i]);
#pragma unroll
            for (int k = 0; k < H; ++k)
                a = __builtin_fmaf(hb[k], Wp[i][k], a);
            float e = fast_exp2(a);
            float r = fast_rcp(e + 1.0f);
            hl[i] = __builtin_fmaf(-2.0f, r, 1.0f);
        }
    }

    // Final FC: per-lane partial dot over owned units, then quad reduction.
    float acc = 0.0f;
#pragma unroll
    for (int i = 0; i < UPL; ++i) {
        const int u = 3 * q + i;
        const float w = (u < H) ? fc_W[u] : 0.0f;
        acc = __builtin_fmaf(hl[i], w, acc);
    }
    acc += quad_swap1(acc);
    acc += quad_swap2(acc);
    if (q == 0) out[b] = acc + fc_b[0];
}

extern "C" void kernel_launch(void* const* d_in, const int* in_sizes, int n_in,
                              void* d_out, int out_size, void* d_ws, size_t ws_size,
                              hipStream_t stream) {
    const float* x    = (const float*)d_in[0];
    const float* W_ih = (const float*)d_in[1];
    const float* W_hh = (const float*)d_in[2];
    const float* b_ih = (const float*)d_in[3];
    const float* b_hh = (const float*)d_in[4];
    const float* fc_W = (const float*)d_in[5];
    const float* fc_b = (const float*)d_in[6];
    float* out = (float*)d_out;

    const int B = out_size;              // 8192
    const int T = in_sizes[0] / B;       // 4096

    const int threads = 64;
    const int total   = B * 4;           // 4 lanes per batch element
    const int blocks  = (total + threads - 1) / threads;
    rnn_quad<<<blocks, threads, 0, stream>>>(x, W_ih, W_hh, b_ih, b_hh,
                                             fc_W, fc_b, out, B, T);
}

// Round 4
// 394.939 us; speedup vs baseline: 3.0785x; 1.1860x over previous
//
#include <hip/hip_runtime.h>

// RNN: h_{t+1} = tanh(x_t * w_in + h_t @ W_hh^T + (b_ih+b_hh)); out = h_T @ fc_W^T + fc_b
// B = out_size (8192), T = in_sizes[0]/B (4096), H = 10.
//
// R4 = R3 with the type fix: h2 must be __fp16 ext_vector(2) to match
// __builtin_amdgcn_cvt_pkrtz's return type on gfx950.
//
// Design: 4 lanes (quad) per element; lane q owns units {q, 4+q, 8+q} (8+q
// dummy for q>=2). Per step, h is exchanged as PACKED fp16 pairs via DPP
// quad_perm (6 DPP + 2 cvt_pkrtz instead of 10 DPP), and the per-unit dot uses
// v_dot2_f32_f16 (fp16 mul, fp32 accumulate) split into 2 independent chains
// to halve both issue and dependency-chain latency. x.w + bias stays fp32.
// tanh(a) = 1 - 2*rcp(exp2(a')+1), weights pre-scaled by 2*log2(e).

#define H 10

typedef __fp16 h2 __attribute__((ext_vector_type(2)));

#if __has_builtin(__builtin_amdgcn_exp2f)
__device__ __forceinline__ float fast_exp2(float x) { return __builtin_amdgcn_exp2f(x); }
#else
__device__ __forceinline__ float fast_exp2(float x) { return __exp2f(x); }
#endif

#if __has_builtin(__builtin_amdgcn_rcpf)
__device__ __forceinline__ float fast_rcp(float x) { return __builtin_amdgcn_rcpf(x); }
#else
__device__ __forceinline__ float fast_rcp(float x) { return 1.0f / x; }
#endif

#if __has_builtin(__builtin_amdgcn_cvt_pkrtz)
__device__ __forceinline__ h2 pk2(float a, float b) { return __builtin_amdgcn_cvt_pkrtz(a, b); }
#else
__device__ __forceinline__ h2 pk2(float a, float b) { h2 r; r.x = (__fp16)a; r.y = (__fp16)b; return r; }
#endif

#if __has_builtin(__builtin_amdgcn_fdot2)
__device__ __forceinline__ float fdot2(h2 a, h2 b, float c) {
    return __builtin_amdgcn_fdot2(a, b, c, false);
}
#else
__device__ __forceinline__ float fdot2(h2 a, h2 b, float c) {
    return (float)a.x * (float)b.x + (float)a.y * (float)b.y + c;
}
#endif

#if __has_builtin(__builtin_amdgcn_mov_dpp)
template <int CTRL>
__device__ __forceinline__ int dpp_i(int v) {
    return __builtin_amdgcn_mov_dpp(v, CTRL, 0xF, 0xF, true);
}
template <int P>
__device__ __forceinline__ float qb_f(float v) {
    return __builtin_bit_cast(float, dpp_i<P * 0x55>(__builtin_bit_cast(int, v)));
}
template <int P>
__device__ __forceinline__ h2 qb_h2(h2 v) {
    return __builtin_bit_cast(h2, dpp_i<P * 0x55>(__builtin_bit_cast(int, v)));
}
__device__ __forceinline__ float qswap1(float v) {
    return __builtin_bit_cast(float, dpp_i<0xB1>(__builtin_bit_cast(int, v)));
}
__device__ __forceinline__ float qswap2(float v) {
    return __builtin_bit_cast(float, dpp_i<0x4E>(__builtin_bit_cast(int, v)));
}
#else
template <int P>
__device__ __forceinline__ float qb_f(float v) { return __shfl(v, (threadIdx.x & ~3) | P, 64); }
template <int P>
__device__ __forceinline__ h2 qb_h2(h2 v) {
    int r = __shfl(__builtin_bit_cast(int, v), (threadIdx.x & ~3) | P, 64);
    return __builtin_bit_cast(h2, r);
}
__device__ __forceinline__ float qswap1(float v) { return __shfl_xor(v, 1, 64); }
__device__ __forceinline__ float qswap2(float v) { return __shfl_xor(v, 2, 64); }
#endif

// One RNN step. Consumes fp32 x sample; updates hl[0..2] (fp32).
// wp[i][j] pairs (W[u][j], W[u][4+j]) j=0..3; wp[i][4] = (W[u][8], W[u][9]).
#define RNN_STEP(XV)                                                          \
    do {                                                                      \
        h2 p_own = pk2(hl[0], hl[1]);                                         \
        h2 pb0 = qb_h2<0>(p_own);                                             \
        h2 pb1 = qb_h2<1>(p_own);                                             \
        h2 pb2 = qb_h2<2>(p_own);                                             \
        h2 pb3 = qb_h2<3>(p_own);                                             \
        h2 p_tail = pk2(qb_f<0>(hl[2]), qb_f<1>(hl[2]));                      \
        _Pragma("unroll")                                                     \
        for (int i = 0; i < 3; ++i) {                                         \
            float a0 = __builtin_fmaf((XV), winp[i], biasp[i]);               \
            a0 = fdot2(pb0, wp[i][0], a0);                                    \
            a0 = fdot2(pb1, wp[i][1], a0);                                    \
            float a1 = fdot2(pb2, wp[i][2], 0.0f);                            \
            a1 = fdot2(pb3, wp[i][3], a1);                                    \
            a1 = fdot2(p_tail, wp[i][4], a1);                                 \
            float a = a0 + a1;                                                \
            float e = fast_exp2(a);                                           \
            float r = fast_rcp(e + 1.0f);                                     \
            hl[i] = __builtin_fmaf(-2.0f, r, 1.0f);                           \
        }                                                                     \
    } while (0)

__global__ __launch_bounds__(64) void rnn_quad_dot2(
    const float* __restrict__ x,
    const float* __restrict__ W_ih,
    const float* __restrict__ W_hh,
    const float* __restrict__ b_ih,
    const float* __restrict__ b_hh,
    const float* __restrict__ fc_W,
    const float* __restrict__ fc_b,
    float* __restrict__ out,
    int B, int T)
{
    const int tid = blockIdx.x * 64 + threadIdx.x;
    const int b   = tid >> 2;      // batch element
    const int q   = tid & 3;       // lane-in-quad
    if (b >= B) return;

    const float C = 2.8853900817779268f;  // 2*log2(e)

    // Lane q owns units u = q, 4+q, 8+q (dummy if >= H -> all-zero weights).
    float winp[3], biasp[3];
    h2 wp[3][5];
#pragma unroll
    for (int i = 0; i < 3; ++i) {
        const int u = 4 * i + q;
        const bool live = (u < H);
        winp[i]  = live ? C * W_ih[u] : 0.0f;
        biasp[i] = live ? C * (b_ih[u] + b_hh[u]) : 0.0f;
#pragma unroll
        for (int j = 0; j < 4; ++j) {
            float w0 = live ? C * W_hh[u * H + j]     : 0.0f;
            float w1 = live ? C * W_hh[u * H + 4 + j] : 0.0f;
            wp[i][j] = pk2(w0, w1);
        }
        {
            float w0 = live ? C * W_hh[u * H + 8] : 0.0f;
            float w1 = live ? C * W_hh[u * H + 9] : 0.0f;
            wp[i][4] = pk2(w0, w1);
        }
    }

    float hl[3] = {0.0f, 0.0f, 0.0f};

    const float* xr = x + (size_t)b * (size_t)T;
    const int T4 = T & ~3;
    float4 xv = make_float4(0.f, 0.f, 0.f, 0.f);
    if (T4 > 0) xv = *(const float4*)(xr);   // all 4 lanes: same address (L1 broadcast)

    for (int t = 0; t < T4; t += 4) {
        float4 xn = xv;
        if (t + 4 < T4) xn = *(const float4*)(xr + t + 4);

        RNN_STEP(xv.x);
        RNN_STEP(xv.y);
        RNN_STEP(xv.z);
        RNN_STEP(xv.w);

        xv = xn;
    }

    for (int t = T4; t < T; ++t) {   // remainder (not taken for T=4096)
        float xq = xr[t];
        RNN_STEP(xq);
    }

    // Final FC: partial dot over owned units (fp32 h), quad reduction.
    float acc = hl[0] * fc_W[q] + hl[1] * fc_W[4 + q];
    if (q < 2) acc = __builtin_fmaf(hl[2], fc_W[8 + q], acc);
    acc += qswap1(acc);
    acc += qswap2(acc);
    if (q == 0) out[b] = acc + fc_b[0];
}

extern "C" void kernel_launch(void* const* d_in, const int* in_sizes, int n_in,
                              void* d_out, int out_size, void* d_ws, size_t ws_size,
                              hipStream_t stream) {
    const float* x    = (const float*)d_in[0];
    const float* W_ih = (const float*)d_in[1];
    const float* W_hh = (const float*)d_in[2];
    const float* b_ih = (const float*)d_in[3];
    const float* b_hh = (const float*)d_in[4];
    const float* fc_W = (const float*)d_in[5];
    const float* fc_b = (const float*)d_in[6];
    float* out = (float*)d_out;

    const int B = out_size;              // 8192
    const int T = in_sizes[0] / B;       // 4096

    const int threads = 64;
    const int total   = B * 4;           // 4 lanes per batch element
    const int blocks  = (total + threads - 1) / threads;
    rnn_quad_dot2<<<blocks, threads, 0, stream>>>(x, W_ih, W_hh, b_ih, b_hh,
                                                  fc_W, fc_b, out, B, T);
}

// Round 6
// 381.839 us; speedup vs baseline: 3.1841x; 1.0343x over previous
//
#include <hip/hip_runtime.h>
#include <stdint.h>

// RNN: h_{t+1} = tanh(x_t * w_in + h_t @ W_hh^T + (b_ih+b_hh)); out = h_T @ fc_W^T + fc_b
// B = out_size (8192), T = in_sizes[0]/B (4096), H = 10.
//
// R6 = R5 with the host/device fix: ONE unconditional kernel; the MFMA
// builtin body is guarded by __HIP_DEVICE_COMPILE__ (host pass compiles a
// dummy body it never runs). R5 crashed because __has_builtin() diverged
// between host and device passes and the host launched a kernel that had
// no device code.
//
// Design: one wave = 16 batch elements via v_mfma_f32_16x16x16_f16.
// Compute Z^T = W * H^T so the MFMA D-fragment layout (row=4*(l>>4)+j,
// col=l&15) is IDENTICAL to the next step's B-fragment layout
// (k=4*(l>>4)+i, col=l&15): the recurrence feeds itself with zero
// cross-lane data movement. Per step: 4 fma (C = x*w_in+bias), 1 MFMA,
// 4x tanh on f32, 2 cvt_pkrtz. A-operand = C*W_hh (fp16, loop-invariant).
// tanh(a) = 1 - 2*rcp(exp2(a')+1), weights pre-scaled by 2*log2(e).

#define H 10

typedef __fp16 h2 __attribute__((ext_vector_type(2)));
typedef __fp16 h4 __attribute__((ext_vector_type(4)));
typedef float  f4 __attribute__((ext_vector_type(4)));

#if __has_builtin(__builtin_amdgcn_exp2f)
__device__ __forceinline__ float fast_exp2(float x) { return __builtin_amdgcn_exp2f(x); }
#else
__device__ __forceinline__ float fast_exp2(float x) { return __exp2f(x); }
#endif

#if __has_builtin(__builtin_amdgcn_rcpf)
__device__ __forceinline__ float fast_rcp(float x) { return __builtin_amdgcn_rcpf(x); }
#else
__device__ __forceinline__ float fast_rcp(float x) { return 1.0f / x; }
#endif

#if __has_builtin(__builtin_amdgcn_cvt_pkrtz)
__device__ __forceinline__ h2 pk2(float a, float b) { return __builtin_amdgcn_cvt_pkrtz(a, b); }
#else
__device__ __forceinline__ h2 pk2(float a, float b) { h2 r; r.x = (__fp16)a; r.y = (__fp16)b; return r; }
#endif

struct hpair { h2 lo, hi; };
__device__ __forceinline__ h4 mk_h4(h2 lo, h2 hi) {
    hpair p; p.lo = lo; p.hi = hi;
    return __builtin_bit_cast(h4, p);
}

// MFMA wrapper: body guarded by device-compile so BOTH passes see the same
// kernel symbol. Host never executes this.
__device__ __forceinline__ f4 mfma_16x16x16f16(h4 a, h4 b, f4 c) {
#if defined(__HIP_DEVICE_COMPILE__)
    return __builtin_amdgcn_mfma_f32_16x16x16f16(a, b, c, 0, 0, 0);
#else
    return c;
#endif
}

// One step: c[j] = x*winp[j]+biasp[j]; d = A*hb + c; h = tanh(d); repack.
#define RNN_STEP(XV)                                                          \
    do {                                                                      \
        f4 c;                                                                 \
        c[0] = __builtin_fmaf((XV), winp[0], biasp[0]);                       \
        c[1] = __builtin_fmaf((XV), winp[1], biasp[1]);                       \
        c[2] = __builtin_fmaf((XV), winp[2], biasp[2]);                       \
        c[3] = __builtin_fmaf((XV), winp[3], biasp[3]);                       \
        f4 d = mfma_16x16x16f16(a_frag, hb, c);                               \
        _Pragma("unroll")                                                     \
        for (int j = 0; j < 4; ++j) {                                         \
            float e = fast_exp2(d[j]);                                        \
            float r = fast_rcp(e + 1.0f);                                     \
            hf[j] = __builtin_fmaf(-2.0f, r, 1.0f);                           \
        }                                                                     \
        hb = mk_h4(pk2(hf[0], hf[1]), pk2(hf[2], hf[3]));                     \
    } while (0)

__global__ __launch_bounds__(64) void rnn_mfma(
    const float* __restrict__ x,
    const float* __restrict__ W_ih,
    const float* __restrict__ W_hh,
    const float* __restrict__ b_ih,
    const float* __restrict__ b_hh,
    const float* __restrict__ fc_W,
    const float* __restrict__ fc_b,
    float* __restrict__ out,
    int B, int T)
{
    const int l = threadIdx.x;    // 0..63 (one wave per block)
    const int n = l & 15;         // batch-within-group (and A-row index)
    const int g = l >> 4;         // k / unit sub-block
    const int b = blockIdx.x * 16 + n;

    const float C = 2.8853900817779268f;  // 2*log2(e)

    // A fragment: A[m][k] = C * W_hh[m][k], fp16. m = l&15, k = 4g+i.
    h4 a_frag;
#pragma unroll
    for (int i = 0; i < 4; ++i) {
        const int k = 4 * g + i;
        const float w = (n < H && k < H) ? C * W_hh[n * H + k] : 0.0f;
        a_frag[i] = (__fp16)w;
    }

    // Per-lane unit-space constants for u = 4g+j (dead units -> 0).
    float winp[4], biasp[4], fcw[4];
#pragma unroll
    for (int j = 0; j < 4; ++j) {
        const int u = 4 * g + j;
        const bool live = (u < H);
        winp[j]  = live ? C * W_ih[u] : 0.0f;
        biasp[j] = live ? C * (b_ih[u] + b_hh[u]) : 0.0f;
        fcw[j]   = live ? fc_W[u] : 0.0f;
    }

    h4 hb = {(__fp16)0.f, (__fp16)0.f, (__fp16)0.f, (__fp16)0.f};  // B fragment (h, fp16)
    float hf[4] = {0.f, 0.f, 0.f, 0.f};                            // h, fp32 (for FC)

    const int brow = (b < B) ? b : (B - 1);
    const float* xr = x + (size_t)brow * (size_t)T;

    const int T4 = T & ~3;
    float4 xv = make_float4(0.f, 0.f, 0.f, 0.f);
    if (T4 > 0) xv = *(const float4*)(xr);   // 4-way lane-replicated (L1 broadcast)

    for (int t = 0; t < T4; t += 4) {
        float4 xn = xv;
        if (t + 4 < T4) xn = *(const float4*)(xr + t + 4);

        RNN_STEP(xv.x);
        RNN_STEP(xv.y);
        RNN_STEP(xv.z);
        RNN_STEP(xv.w);

        xv = xn;
    }
    for (int t = T4; t < T; ++t) {   // remainder (not taken for T=4096)
        float xq = xr[t];
        RNN_STEP(xq);
    }

    // FC: partial over this lane's 4 units, reduce across the 4 g-groups.
    float acc = hf[0] * fcw[0] + hf[1] * fcw[1] + hf[2] * fcw[2] + hf[3] * fcw[3];
    acc += __shfl_xor(acc, 16, 64);
    acc += __shfl_xor(acc, 32, 64);
    if (g == 0 && b < B) out[b] = acc + fc_b[0];
}

extern "C" void kernel_launch(void* const* d_in, const int* in_sizes, int n_in,
                              void* d_out, int out_size, void* d_ws, size_t ws_size,
                              hipStream_t stream) {
    const float* x    = (const float*)d_in[0];
    const float* W_ih = (const float*)d_in[1];
    const float* W_hh = (const float*)d_in[2];
    const float* b_ih = (const float*)d_in[3];
    const float* b_hh = (const float*)d_in[4];
    const float* fc_W = (const float*)d_in[5];
    const float* fc_b = (const float*)d_in[6];
    float* out = (float*)d_out;

    const int B = out_size;              // 8192
    const int T = in_sizes[0] / B;       // 4096

    const int blocks = (B + 15) / 16;    // one wave = 16 batch elements
    rnn_mfma<<<blocks, 64, 0, stream>>>(x, W_ih, W_hh, b_ih, b_hh,
                                        fc_W, fc_b, out, B, T);
}

// Round 7
// 306.154 us; speedup vs baseline: 3.9713x; 1.2472x over previous
//
#include <hip/hip_runtime.h>
#include <stdint.h>

// RNN: h_{t+1} = tanh(x_t * w_in + h_t @ W_hh^T + (b_ih+b_hh)); out = h_T @ fc_W^T + fc_b
// B = out_size (8192), T = in_sizes[0]/B (4096), H = 10.
//
// R7 design (builds on R6's self-feeding MFMA):
//  * r-recursion: track r_t = 1/(1+exp2(a_t)) (h = 1-2r). Fold -2 into the
//    MFMA A-operand (M = -2C*W_hh) and the W-rowsum into the bias:
//       a_{t+1} = C(x w_in + b + W*1) + M r_t
//    Critical path per step: MFMA -> exp2 -> add -> rcp -> cvt_pkrtz -> MFMA
//    (the 1-2r fma is gone from the loop).
//  * x consumed in 8-step blocks with a depth-2 software pipeline (loads
//    issued ~2 blocks = ~3800 cy before use, distinct registers, branch-free
//    inner loop) so HBM/L3 load latency is never on the recurrence path.
//  * One wave = 16 batch elements; D-fragment layout of mfma_f32_16x16x16f16
//    (row=4*(l>>4)+j, col=l&15) == its B-fragment layout -> zero cross-lane
//    data movement per step.

#define H 10

typedef __fp16 h2 __attribute__((ext_vector_type(2)));
typedef __fp16 h4 __attribute__((ext_vector_type(4)));
typedef float  f4 __attribute__((ext_vector_type(4)));

#if __has_builtin(__builtin_amdgcn_exp2f)
__device__ __forceinline__ float fast_exp2(float x) { return __builtin_amdgcn_exp2f(x); }
#else
__device__ __forceinline__ float fast_exp2(float x) { return __exp2f(x); }
#endif

#if __has_builtin(__builtin_amdgcn_rcpf)
__device__ __forceinline__ float fast_rcp(float x) { return __builtin_amdgcn_rcpf(x); }
#else
__device__ __forceinline__ float fast_rcp(float x) { return 1.0f / x; }
#endif

#if __has_builtin(__builtin_amdgcn_cvt_pkrtz)
__device__ __forceinline__ h2 pk2(float a, float b) { return __builtin_amdgcn_cvt_pkrtz(a, b); }
#else
__device__ __forceinline__ h2 pk2(float a, float b) { h2 r; r.x = (__fp16)a; r.y = (__fp16)b; return r; }
#endif

struct hpair { h2 lo, hi; };
__device__ __forceinline__ h4 mk_h4(h2 lo, h2 hi) {
    hpair p; p.lo = lo; p.hi = hi;
    return __builtin_bit_cast(h4, p);
}

// MFMA wrapper: body guarded by device-compile so BOTH passes see the same
// kernel symbol (R5 lesson: __has_builtin diverges host vs device).
__device__ __forceinline__ f4 mfma_16x16x16f16(h4 a, h4 b, f4 c) {
#if defined(__HIP_DEVICE_COMPILE__)
    return __builtin_amdgcn_mfma_f32_16x16x16f16(a, b, c, 0, 0, 0);
#else
    return c;
#endif
}

// One step of the r-recursion. rb: packed fp16 r (B fragment).
// rf[j]: fp32 r of this lane's 4 units (live across steps for the epilogue).
#define RNN_STEP(XV)                                                          \
    do {                                                                      \
        f4 c;                                                                 \
        c[0] = __builtin_fmaf((XV), winp[0], biasc[0]);                       \
        c[1] = __builtin_fmaf((XV), winp[1], biasc[1]);                       \
        c[2] = __builtin_fmaf((XV), winp[2], biasc[2]);                       \
        c[3] = __builtin_fmaf((XV), winp[3], biasc[3]);                       \
        f4 d = mfma_16x16x16f16(m_frag, rb, c);                               \
        _Pragma("unroll")                                                     \
        for (int j = 0; j < 4; ++j) {                                         \
            float e = fast_exp2(d[j]);                                        \
            rf[j] = fast_rcp(e + 1.0f);                                       \
        }                                                                     \
        rb = mk_h4(pk2(rf[0], rf[1]), pk2(rf[2], rf[3]));                     \
    } while (0)

#define STEP8(V0, V1)                                                         \
    do {                                                                      \
        RNN_STEP((V0).x); RNN_STEP((V0).y); RNN_STEP((V0).z); RNN_STEP((V0).w); \
        RNN_STEP((V1).x); RNN_STEP((V1).y); RNN_STEP((V1).z); RNN_STEP((V1).w); \
    } while (0)

__global__ __launch_bounds__(64) void rnn_mfma_r(
    const float* __restrict__ x,
    const float* __restrict__ W_ih,
    const float* __restrict__ W_hh,
    const float* __restrict__ b_ih,
    const float* __restrict__ b_hh,
    const float* __restrict__ fc_W,
    const float* __restrict__ fc_b,
    float* __restrict__ out,
    int B, int T)
{
    const int l = threadIdx.x;    // 0..63 (one wave per block)
    const int n = l & 15;         // batch-within-group; also A-row (output unit index m)
    const int g = l >> 4;         // k / unit sub-block
    const int b = blockIdx.x * 16 + n;

    const float C = 2.8853900817779268f;  // 2*log2(e)

    // A fragment: M[m][k] = -2*C*W_hh[m][k], fp16. m = n, k = 4g+i.
    h4 m_frag;
#pragma unroll
    for (int i = 0; i < 4; ++i) {
        const int k = 4 * g + i;
        const float w = (n < H && k < H) ? -2.0f * C * W_hh[n * H + k] : 0.0f;
        m_frag[i] = (__fp16)w;
    }

    // Per-lane constants for unit u = 4g+j (dead units -> 0):
    // biasc = C*(b_ih+b_hh + rowsum(W_hh)), winp = C*W_ih, fcw = fc_W.
    float winp[4], biasc[4], fcw[4];
#pragma unroll
    for (int j = 0; j < 4; ++j) {
        const int u = 4 * g + j;
        const bool live = (u < H);
        float rowsum = 0.0f;
        if (live) {
#pragma unroll
            for (int k = 0; k < H; ++k) rowsum += W_hh[u * H + k];
        }
        winp[j]  = live ? C * W_ih[u] : 0.0f;
        biasc[j] = live ? C * (b_ih[u] + b_hh[u] + rowsum) : 0.0f;
        fcw[j]   = live ? fc_W[u] : 0.0f;
    }

    // r = 1/(1+exp2(a)); h=0 <=> r=1/2.
    const __fp16 half16 = (__fp16)0.5f;
    h4 rb = {half16, half16, half16, half16};       // B fragment (fp16 r)
    float rf[4] = {0.5f, 0.5f, 0.5f, 0.5f};        // fp32 r (epilogue)

    const int brow = (b < B) ? b : (B - 1);
    const float* xr = x + (size_t)brow * (size_t)T;

    // ---- main loop: 8-step blocks, depth-2 pipelined x loads ----
    int t = 0;
    if (((T & 7) == 0) && T >= 24) {
        const int nb = T >> 3;   // number of 8-step blocks (>= 3 here)
        float4 a0 = *(const float4*)(xr + 0);
        float4 a1 = *(const float4*)(xr + 4);
        float4 b0 = *(const float4*)(xr + 8);
        float4 b1 = *(const float4*)(xr + 12);
        for (int blk = 0; blk < nb - 2; ++blk) {
            const float* xf = xr + 8 * (blk + 2);
            float4 f0 = *(const float4*)(xf);
            float4 f1 = *(const float4*)(xf + 4);
            STEP8(a0, a1);
            a0 = b0; a1 = b1;
            b0 = f0; b1 = f1;
        }
        STEP8(a0, a1);
        STEP8(b0, b1);
        t = T;
    }
    for (; t < T; ++t) {          // generic fallback / remainder
        float xq = xr[t];
        RNN_STEP(xq);
    }

    // Epilogue: h = 1 - 2r; FC partial over this lane's 4 units, reduce over g.
    float acc = 0.0f;
#pragma unroll
    for (int j = 0; j < 4; ++j) {
        const float h = __builtin_fmaf(-2.0f, rf[j], 1.0f);
        acc = __builtin_fmaf(h, fcw[j], acc);
    }
    acc += __shfl_xor(acc, 16, 64);
    acc += __shfl_xor(acc, 32, 64);
    if (g == 0 && b < B) out[b] = acc + fc_b[0];
}

extern "C" void kernel_launch(void* const* d_in, const int* in_sizes, int n_in,
                              void* d_out, int out_size, void* d_ws, size_t ws_size,
                              hipStream_t stream) {
    const float* x    = (const float*)d_in[0];
    const float* W_ih = (const float*)d_in[1];
    const float* W_hh = (const float*)d_in[2];
    const float* b_ih = (const float*)d_in[3];
    const float* b_hh = (const float*)d_in[4];
    const float* fc_W = (const float*)d_in[5];
    const float* fc_b = (const float*)d_in[6];
    float* out = (float*)d_out;

    const int B = out_size;              // 8192
    const int T = in_sizes[0] / B;       // 4096

    const int blocks = (B + 15) / 16;    // one wave = 16 batch elements
    rnn_mfma_r<<<blocks, 64, 0, stream>>>(x, W_ih, W_hh, b_ih, b_hh,
                                          fc_W, fc_b, out, B, T);
}